// Round 1
// baseline (400.996 us; speedup 1.0000x reference)
//
#include <hip/hip_runtime.h>
#include <cmath>

// Problem constants (from reference):
//   F=26 features, B=16384 batch, V=100000 vocab/table, D=32 embed dim, H=13
constexpr int F = 26;
constexpr int B = 16384;
constexpr int V = 100000;
constexpr int D = 32;
constexpr int H = 13;

// ---------------------------------------------------------------------------
// Kernel 1: compute scale[F] = sigmoid(w2 @ relu(w1 @ se_last))
// where se_last[f] = mean_d emb_tables[f, x[f, B-1], d].
// Only the LAST batch row's gates are used by the reference (gate[-1]),
// so the entire SE-net over the batch collapses to this tiny kernel.
// One block of 64 threads; writes F floats to d_ws.
// ---------------------------------------------------------------------------
__global__ void se_scale_kernel(const int* __restrict__ x,
                                const float* __restrict__ tables,
                                const float* __restrict__ w1,
                                const float* __restrict__ w2,
                                float* __restrict__ scale) {
    __shared__ float se[F];
    __shared__ float h[H];
    const int t = threadIdx.x;

    if (t < F) {
        const int idx = x[t * B + (B - 1)];
        const float* row = tables + (size_t)t * V * D + (size_t)idx * D;
        float s = 0.0f;
#pragma unroll
        for (int d = 0; d < D; ++d) s += row[d];
        se[t] = s * (1.0f / (float)D);
    }
    __syncthreads();

    if (t < H) {
        float a = 0.0f;
#pragma unroll
        for (int f = 0; f < F; ++f) a += w1[t * F + f] * se[f];
        h[t] = a > 0.0f ? a : 0.0f;  // relu
    }
    __syncthreads();

    if (t < F) {
        float a = 0.0f;
#pragma unroll
        for (int j = 0; j < H; ++j) a += w2[t * H + j] * h[j];
        scale[t] = 1.0f / (1.0f + expf(-a));  // sigmoid
    }
}

// ---------------------------------------------------------------------------
// Kernel 2: out[b, f*D+d] = tables[f, x[f,b], d] * scale[f]
// One thread per float4. Flat index g over B*F*D/4 = 3,407,872 float4s:
//   b = g / 208, r = g % 208 (F*D/4 = 208), f = r>>3, d4 = r&7.
// Each 8-lane group reads one contiguous 128B (128B-aligned) table row;
// writes are fully coalesced float4 stores to d_out.
// ---------------------------------------------------------------------------
constexpr int F4_PER_B = F * D / 4;  // 208 float4 per batch row
constexpr int TOTAL_F4 = B * F4_PER_B;

__global__ __launch_bounds__(256) void gather_scale_kernel(
        const int* __restrict__ x,
        const float4* __restrict__ tables4,
        const float* __restrict__ scale,
        float4* __restrict__ out4) {
    const int g = blockIdx.x * 256 + threadIdx.x;
    const int b = g / F4_PER_B;               // magic-mul division
    const int r = g - b * F4_PER_B;
    const int f = r >> 3;
    const int d4 = r & 7;

    const int idx = x[f * B + b];             // broadcast within each 8-lane group
    float4 v = tables4[f * (V * D / 4) + idx * (D / 4) + d4];
    const float s = scale[f];
    v.x *= s; v.y *= s; v.z *= s; v.w *= s;
    out4[g] = v;
}

extern "C" void kernel_launch(void* const* d_in, const int* in_sizes, int n_in,
                              void* d_out, int out_size, void* d_ws, size_t ws_size,
                              hipStream_t stream) {
    const int*   x      = (const int*)d_in[0];     // [F, B] int32
    const float* tables = (const float*)d_in[1];   // [F, V, D] fp32
    const float* w1     = (const float*)d_in[2];   // [H, F] fp32
    const float* w2     = (const float*)d_in[3];   // [F, H] fp32
    float*       out    = (float*)d_out;           // [B, F*D] fp32
    float*       scale  = (float*)d_ws;            // F floats of scratch

    se_scale_kernel<<<1, 64, 0, stream>>>(x, tables, w1, w2, scale);

    const int grid = TOTAL_F4 / 256;  // 13312 blocks, exact
    gather_scale_kernel<<<grid, 256, 0, stream>>>(
        x, (const float4*)tables, scale, (float4*)out);
}